// Round 13
// baseline (432.757 us; speedup 1.0000x reference)
//
#include <hip/hip_runtime.h>
#include <math.h>

#define NBLEND 24
#define HDIM 128
#define KQ 32                    // k-columns per wave (4-way split)
#define MAX_STEPS 10
#define CVG_T 1e-5f
#define DVG_T 1.0f
#define EPS_B 1e-6f

typedef float v2f __attribute__((ext_vector_type(2)));

#if __has_builtin(__builtin_elementwise_fma)
#define VFMA(a, b, c) __builtin_elementwise_fma((a), (b), (c))
#else
static __device__ __forceinline__ v2f VFMA(v2f a, v2f b, v2f c) {
    v2f r; r.x = fmaf(a.x, b.x, c.x); r.y = fmaf(a.y, b.y, c.y); return r;
}
#endif

__device__ __forceinline__ float softplus_f(float x) {
    // jax.nn.softplus: max(x,0) + log1p(exp(-|x|)), numerically stable
    float e = __expf(-fabsf(x));
    return fmaxf(x, 0.0f) + __logf(1.0f + e);
}

// One g(x) evaluation, split across the block's FOUR waves (R12 body —
// measured 86% VALUBusy, executed-FLOP roofline closed): wave w handles
// k in [w*32, w*32+32) for the same 64 points (one per lane). Weights on
// the wave-uniform scalar path (SGPR broadcast free; VMEM/LDS broadcast
// measured slower, R7/R10). Partial logits all-to-all via LDS in FIXED
// order so all four waves compute bit-identical g.
__device__ __forceinline__ void eval_g_quad(
    v2f (&part)[4][NBLEND / 2][64],
    int w, int lane,
    const float* __restrict__ W0, const float* __restrict__ b0,
    const float* __restrict__ W1, const float* __restrict__ b1,
    const float* __restrict__ W2, const float* __restrict__ b2,
    const float* __restrict__ tfs,
    float x0, float x1, float x2,
    float xd0, float xd1, float xd2,
    float& g0, float& g1, float& g2)
{
    v2f acc[KQ / 2];
    {
        const v2f* __restrict__ b1v = (const v2f*)(b1 + w * KQ);
        #pragma unroll
        for (int kk = 0; kk < KQ / 2; ++kk) acc[kk] = b1v[kk];
    }
    const float* __restrict__ W1h = W1 + w * KQ;
    v2f vx0 = {x0, x0}, vx1 = {x1, x1}, vx2 = {x2, x2};

    #pragma unroll 2
    for (int j = 0; j < HDIM; j += 2) {
        v2f z = *(const v2f*)(b0 + j);
        z = VFMA(vx0, *(const v2f*)(W0 + j), z);
        z = VFMA(vx1, *(const v2f*)(W0 + HDIM + j), z);
        z = VFMA(vx2, *(const v2f*)(W0 + 2 * HDIM + j), z);
        float ha = softplus_f(z.x);
        float hb = softplus_f(z.y);
        const v2f* __restrict__ r0 = (const v2f*)(W1h + j * HDIM);
        const v2f* __restrict__ r1 = (const v2f*)(W1h + (j + 1) * HDIM);
        v2f hva = {ha, ha}, hvb = {hb, hb};
        #pragma unroll
        for (int kk = 0; kk < KQ / 2; ++kk) acc[kk] = VFMA(hva, r0[kk], acc[kk]);
        #pragma unroll
        for (int kk = 0; kk < KQ / 2; ++kk) acc[kk] = VFMA(hvb, r1[kk], acc[kk]);
    }
    #pragma unroll
    for (int kk = 0; kk < KQ / 2; ++kk) {
        acc[kk].x = softplus_f(acc[kk].x);
        acc[kk].y = softplus_f(acc[kk].y);
    }

    // raw partial logits over own k-slice (b2 added in fixed order below)
    v2f lgp[NBLEND / 2];
    #pragma unroll
    for (int m2 = 0; m2 < NBLEND / 2; ++m2) lgp[m2] = (v2f){0.f, 0.f};
    const float* __restrict__ W2h = W2 + w * KQ * NBLEND;
    #pragma unroll
    for (int kk = 0; kk < KQ; ++kk) {
        float h1 = (kk & 1) ? acc[kk >> 1].y : acc[kk >> 1].x;
        v2f hv = {h1, h1};
        const v2f* __restrict__ w2r = (const v2f*)(W2h + kk * NBLEND);
        #pragma unroll
        for (int m2 = 0; m2 < NBLEND / 2; ++m2) lgp[m2] = VFMA(hv, w2r[m2], lgp[m2]);
    }

    // all-to-all exchange; every wave sums in the SAME order -> identical g
    #pragma unroll
    for (int m2 = 0; m2 < NBLEND / 2; ++m2) part[w][m2][lane] = lgp[m2];
    __syncthreads();
    v2f lg[NBLEND / 2];
    {
        const v2f* __restrict__ b2v = (const v2f*)b2;
        #pragma unroll
        for (int m2 = 0; m2 < NBLEND / 2; ++m2)
            lg[m2] = ((b2v[m2] + part[0][m2][lane]) + part[1][m2][lane])
                     + (part[2][m2][lane] + part[3][m2][lane]);
    }
    __syncthreads();   // WAR: safe to overwrite part[] on the next eval

    // two-pass softmax over 24 logits (matches jax.nn.softmax)
    float M = -3.0e38f;
    #pragma unroll
    for (int m2 = 0; m2 < NBLEND / 2; ++m2)
        M = fmaxf(M, fmaxf(lg[m2].x, lg[m2].y));

    float S = 0.f;
    v2f T[6];
    #pragma unroll
    for (int t = 0; t < 6; ++t) T[t] = (v2f){0.f, 0.f};
    #pragma unroll
    for (int m = 0; m < NBLEND; ++m) {
        float lgm = (m & 1) ? lg[m >> 1].y : lg[m >> 1].x;
        float e = __expf(lgm - M);
        S += e;
        const v2f* __restrict__ tf = (const v2f*)(tfs + m * 12);
        v2f ev = {e, e};
        #pragma unroll
        for (int t = 0; t < 6; ++t) T[t] = VFMA(ev, tf[t], T[t]);
    }
    float inv = 1.0f / S;
    g0 = inv * fmaf(T[0].x, x0, fmaf(T[0].y, x1, fmaf(T[1].x, x2, T[1].y))) - xd0;
    g1 = inv * fmaf(T[2].x, x0, fmaf(T[2].y, x1, fmaf(T[3].x, x2, T[3].y))) - xd1;
    g2 = inv * fmaf(T[4].x, x0, fmaf(T[4].y, x1, fmaf(T[5].x, x2, T[5].y))) - xd2;
}

struct PState {
    float x0, x1, x2;
    float g0, g1, g2;
    float J[9];
    float u0, u1, u2;
    float xo0, xo1, xo2;
    float gno;
};

// One Broyden step (reference semantics, verified R1-R12). active=false is
// an exact per-lane freeze (dx=0 -> dg=0 -> a=0 -> iu=0 -> state fixed;
// NaN guarded by selects). Contains ONE eval call site.
__device__ __forceinline__ bool do_step_quad(
    bool active,
    v2f (&part)[4][NBLEND / 2][64], int w, int lane,
    const float* __restrict__ W0, const float* __restrict__ b0,
    const float* __restrict__ W1, const float* __restrict__ b1,
    const float* __restrict__ W2, const float* __restrict__ b2,
    const float* __restrict__ tfs,
    float xd0, float xd1, float xd2, PState& s)
{
    float dx0 = active ? s.u0 : 0.f;
    float dx1 = active ? s.u1 : 0.f;
    float dx2 = active ? s.u2 : 0.f;
    s.x0 += dx0; s.x1 += dx1; s.x2 += dx2;

    float ng0, ng1, ng2;
    eval_g_quad(part, w, lane, W0, b0, W1, b1, W2, b2, tfs,
                s.x0, s.x1, s.x2, xd0, xd1, xd2, ng0, ng1, ng2);
    float dg0 = ng0 - s.g0, dg1 = ng1 - s.g1, dg2 = ng2 - s.g2;
    s.g0 = ng0; s.g1 = ng1; s.g2 = ng2;

    float gn = sqrtf(s.g0 * s.g0 + s.g1 * s.g1 + s.g2 * s.g2);
    bool better = gn < s.gno;                 // false for NaN (matches jnp.where)
    if (better) { s.gno = gn; s.xo0 = s.x0; s.xo1 = s.x1; s.xo2 = s.x2; }
    bool ids_new = (s.gno > CVG_T) && (gn < DVG_T);

    float vT0 = fmaf(dx0, s.J[0], fmaf(dx1, s.J[3], dx2 * s.J[6]));
    float vT1 = fmaf(dx0, s.J[1], fmaf(dx1, s.J[4], dx2 * s.J[7]));
    float vT2 = fmaf(dx0, s.J[2], fmaf(dx1, s.J[5], dx2 * s.J[8]));
    float a0 = dx0 - fmaf(s.J[0], dg0, fmaf(s.J[1], dg1, s.J[2] * dg2));
    float a1 = dx1 - fmaf(s.J[3], dg0, fmaf(s.J[4], dg1, s.J[5] * dg2));
    float a2 = dx2 - fmaf(s.J[6], dg0, fmaf(s.J[7], dg1, s.J[8] * dg2));
    float bb = fmaf(vT0, dg0, fmaf(vT1, dg1, vT2 * dg2));
    bb += (bb >= 0.f) ? EPS_B : -EPS_B;
    float iu0 = ids_new ? (a0 / bb) : 0.f;
    float iu1 = ids_new ? (a1 / bb) : 0.f;
    float iu2 = ids_new ? (a2 / bb) : 0.f;
    s.J[0] = fmaf(iu0, vT0, s.J[0]); s.J[1] = fmaf(iu0, vT1, s.J[1]); s.J[2] = fmaf(iu0, vT2, s.J[2]);
    s.J[3] = fmaf(iu1, vT0, s.J[3]); s.J[4] = fmaf(iu1, vT1, s.J[4]); s.J[5] = fmaf(iu1, vT2, s.J[5]);
    s.J[6] = fmaf(iu2, vT0, s.J[6]); s.J[7] = fmaf(iu2, vT1, s.J[7]); s.J[8] = fmaf(iu2, vT2, s.J[8]);

    s.u0 = -(fmaf(s.J[0], s.g0, fmaf(s.J[1], s.g1, s.J[2] * s.g2)));
    s.u1 = -(fmaf(s.J[3], s.g0, fmaf(s.J[4], s.g1, s.J[5] * s.g2)));
    s.u2 = -(fmaf(s.J[6], s.g0, fmaf(s.J[7], s.g1, s.J[8] * s.g2)));
    return ids_new;
}

// --- state SoA in d_ws: 22 arrays of N floats ---
// 0-2: x | 3-11: J | 12-14: g | 15-17: u | 18-20: xo | 21: gno

__device__ __forceinline__ void st_store(float* __restrict__ st, int N, int n,
                                         const PState& s) {
    st[0 * N + n] = s.x0; st[1 * N + n] = s.x1; st[2 * N + n] = s.x2;
    #pragma unroll
    for (int a = 0; a < 9; ++a) st[(3 + a) * N + n] = s.J[a];
    st[12 * N + n] = s.g0; st[13 * N + n] = s.g1; st[14 * N + n] = s.g2;
    st[15 * N + n] = s.u0; st[16 * N + n] = s.u1; st[17 * N + n] = s.u2;
    st[18 * N + n] = s.xo0; st[19 * N + n] = s.xo1; st[20 * N + n] = s.xo2;
    st[21 * N + n] = s.gno;
}

__device__ __forceinline__ void st_load(const float* __restrict__ st, int N, int n,
                                        PState& s) {
    s.x0 = st[0 * N + n]; s.x1 = st[1 * N + n]; s.x2 = st[2 * N + n];
    #pragma unroll
    for (int a = 0; a < 9; ++a) s.J[a] = st[(3 + a) * N + n];
    s.g0 = st[12 * N + n]; s.g1 = st[13 * N + n]; s.g2 = st[14 * N + n];
    s.u0 = st[15 * N + n]; s.u1 = st[16 * N + n]; s.u2 = st[17 * N + n];
    s.xo0 = st[18 * N + n]; s.xo1 = st[19 * N + n]; s.xo2 = st[20 * N + n];
    s.gno = st[21 * N + n];
}

__device__ __forceinline__ void write_out(float* __restrict__ out, int N, int n,
                                          const PState& s) {
    out[n * 3 + 0] = s.xo0;
    out[n * 3 + 1] = s.xo1;
    out[n * 3 + 2] = s.xo2;
    out[3 * N + n] = s.gno;
    out[4 * N + n] = (s.gno < CVG_T) ? 1.0f : 0.0f;
}

// eval0 + step1, explicit (2 eval sites — rolling costs VALU, R11)
__global__ void __launch_bounds__(256)
init_step1_kernel(const float* __restrict__ xd_p,
                  const float* __restrict__ x_init,
                  const float* __restrict__ Jinv_init,
                  const float* __restrict__ tfs,
                  const float* __restrict__ W0, const float* __restrict__ b0,
                  const float* __restrict__ W1, const float* __restrict__ b1,
                  const float* __restrict__ W2, const float* __restrict__ b2,
                  float* __restrict__ out, float* __restrict__ st,
                  int* __restrict__ qout, int* __restrict__ cnt_out, int N)
{
    __shared__ v2f part[4][NBLEND / 2][64];
    const int tid = threadIdx.x;
    const int lane = tid & 63;
    const int w = __builtin_amdgcn_readfirstlane(tid >> 6);   // 0..3
    const int n = blockIdx.x * 64 + lane;   // N = 131072 = 2048*64 exact

    float xd0 = xd_p[n * 3 + 0], xd1 = xd_p[n * 3 + 1], xd2 = xd_p[n * 3 + 2];
    PState s;
    s.x0 = x_init[n * 3 + 0]; s.x1 = x_init[n * 3 + 1]; s.x2 = x_init[n * 3 + 2];
    #pragma unroll
    for (int a = 0; a < 9; ++a) s.J[a] = Jinv_init[n * 9 + a];

    eval_g_quad(part, w, lane, W0, b0, W1, b1, W2, b2, tfs,
                s.x0, s.x1, s.x2, xd0, xd1, xd2, s.g0, s.g1, s.g2);
    s.u0 = -(fmaf(s.J[0], s.g0, fmaf(s.J[1], s.g1, s.J[2] * s.g2)));
    s.u1 = -(fmaf(s.J[3], s.g0, fmaf(s.J[4], s.g1, s.J[5] * s.g2)));
    s.u2 = -(fmaf(s.J[6], s.g0, fmaf(s.J[7], s.g1, s.J[8] * s.g2)));
    s.gno = sqrtf(s.g0 * s.g0 + s.g1 * s.g1 + s.g2 * s.g2);
    s.xo0 = s.x0; s.xo1 = s.x1; s.xo2 = s.x2;

    bool alive = do_step_quad(true, part, w, lane, W0, b0, W1, b1, W2, b2, tfs,
                              xd0, xd1, xd2, s);
    if (w == 0) {
        if (alive) {
            int pos = atomicAdd(cnt_out, 1);
            qout[pos] = n;
            st_store(st, N, n, s);
        } else {
            write_out(out, N, n, s);
        }
    }
}

// one compacted step (steps 2 and 3)
__global__ void __launch_bounds__(256)
step_kernel(const float* __restrict__ xd_p,
            const float* __restrict__ tfs,
            const float* __restrict__ W0, const float* __restrict__ b0,
            const float* __restrict__ W1, const float* __restrict__ b1,
            const float* __restrict__ W2, const float* __restrict__ b2,
            float* __restrict__ out, float* __restrict__ st,
            const int* __restrict__ qin, const int* __restrict__ cnt_in,
            int* __restrict__ qout, int* __restrict__ cnt_out, int N)
{
    __shared__ v2f part[4][NBLEND / 2][64];
    const int count = *cnt_in;                       // uniform -> s_load
    const int b = blockIdx.x;
    if (b * 64 >= count) return;                     // block-uniform exit
    const int tid = threadIdx.x;
    const int lane = tid & 63;
    const int w = __builtin_amdgcn_readfirstlane(tid >> 6);
    const int i = b * 64 + lane;
    const bool valid = i < count;
    const int qi = valid ? i : (count - 1);          // dummy lanes: barriers uniform
    const int n = qin[qi];

    float xd0 = xd_p[n * 3 + 0], xd1 = xd_p[n * 3 + 1], xd2 = xd_p[n * 3 + 2];
    PState s;
    st_load(st, N, n, s);

    bool alive = do_step_quad(true, part, w, lane, W0, b0, W1, b1, W2, b2, tfs,
                              xd0, xd1, xd2, s);
    if (w == 0 && valid) {
        if (alive) {
            int pos = atomicAdd(cnt_out, 1);
            qout[pos] = n;
            st_store(st, N, n, s);
        } else {
            write_out(out, N, n, s);
        }
    }
}

// merged tail: steps 4..MAX_STEPS in one kernel, internal ballot-exit loop
__global__ void __launch_bounds__(256)
tail_kernel(const float* __restrict__ xd_p,
            const float* __restrict__ tfs,
            const float* __restrict__ W0, const float* __restrict__ b0,
            const float* __restrict__ W1, const float* __restrict__ b1,
            const float* __restrict__ W2, const float* __restrict__ b2,
            float* __restrict__ out, float* __restrict__ st,
            const int* __restrict__ qin, const int* __restrict__ cnt_in, int N)
{
    __shared__ v2f part[4][NBLEND / 2][64];
    const int count = *cnt_in;
    const int b = blockIdx.x;
    if (b * 64 >= count) return;
    const int tid = threadIdx.x;
    const int lane = tid & 63;
    const int w = __builtin_amdgcn_readfirstlane(tid >> 6);
    const int i = b * 64 + lane;
    const bool valid = i < count;
    const int qi = valid ? i : (count - 1);
    const int n = qin[qi];

    float xd0 = xd_p[n * 3 + 0], xd1 = xd_p[n * 3 + 1], xd2 = xd_p[n * 3 + 2];
    PState s;
    st_load(st, N, n, s);

    bool alive = true;   // queued points are alive by construction
    #pragma unroll 1
    for (int it = 0; it < MAX_STEPS - 3; ++it) {
        // all 4 waves hold identical per-lane alive -> uniform ballot/break
        if (__ballot(alive) == 0ull) break;
        bool r = do_step_quad(alive, part, w, lane, W0, b0, W1, b1, W2, b2, tfs,
                              xd0, xd1, xd2, s);
        alive = alive && r;
    }
    if (w == 0 && valid) write_out(out, N, n, s);
}

// fallback: monolithic quad (R12 kernel), used only if d_ws too small
__global__ void __launch_bounds__(256)
broyden_mono_kernel(const float* __restrict__ xd_p,
                    const float* __restrict__ x_init,
                    const float* __restrict__ Jinv_init,
                    const float* __restrict__ tfs,
                    const float* __restrict__ W0, const float* __restrict__ b0,
                    const float* __restrict__ W1, const float* __restrict__ b1,
                    const float* __restrict__ W2, const float* __restrict__ b2,
                    float* __restrict__ out, int N)
{
    __shared__ v2f part[4][NBLEND / 2][64];
    const int tid = threadIdx.x;
    const int lane = tid & 63;
    const int w = __builtin_amdgcn_readfirstlane(tid >> 6);
    const int n = blockIdx.x * 64 + lane;

    float xd0 = xd_p[n * 3 + 0], xd1 = xd_p[n * 3 + 1], xd2 = xd_p[n * 3 + 2];
    PState s;
    s.x0 = x_init[n * 3 + 0]; s.x1 = x_init[n * 3 + 1]; s.x2 = x_init[n * 3 + 2];
    #pragma unroll
    for (int a = 0; a < 9; ++a) s.J[a] = Jinv_init[n * 9 + a];

    eval_g_quad(part, w, lane, W0, b0, W1, b1, W2, b2, tfs,
                s.x0, s.x1, s.x2, xd0, xd1, xd2, s.g0, s.g1, s.g2);
    s.u0 = -(fmaf(s.J[0], s.g0, fmaf(s.J[1], s.g1, s.J[2] * s.g2)));
    s.u1 = -(fmaf(s.J[3], s.g0, fmaf(s.J[4], s.g1, s.J[5] * s.g2)));
    s.u2 = -(fmaf(s.J[6], s.g0, fmaf(s.J[7], s.g1, s.J[8] * s.g2)));
    s.gno = sqrtf(s.g0 * s.g0 + s.g1 * s.g1 + s.g2 * s.g2);
    s.xo0 = s.x0; s.xo1 = s.x1; s.xo2 = s.x2;

    bool ids = true;
    for (int step = 0; step < MAX_STEPS; ++step) {
        if (__ballot(ids) == 0ull) break;
        bool r = do_step_quad(ids, part, w, lane, W0, b0, W1, b1, W2, b2, tfs,
                              xd0, xd1, xd2, s);
        ids = ids && r;
    }
    if (w == 0) write_out(out, N, n, s);
}

extern "C" void kernel_launch(void* const* d_in, const int* in_sizes, int n_in,
                              void* d_out, int out_size, void* d_ws, size_t ws_size,
                              hipStream_t stream) {
    const float* xd     = (const float*)d_in[0];
    const float* x_init = (const float*)d_in[1];
    const float* Jinv   = (const float*)d_in[2];
    const float* tfs    = (const float*)d_in[3];
    const float* W0     = (const float*)d_in[4];
    const float* b0     = (const float*)d_in[5];
    const float* W1     = (const float*)d_in[6];
    const float* b1     = (const float*)d_in[7];
    const float* W2     = (const float*)d_in[8];
    const float* b2     = (const float*)d_in[9];
    float* out = (float*)d_out;

    const int N = in_sizes[0] / 3;
    const int nb = (N + 63) / 64;      // 256-thread blocks, 64 points each
    const size_t need = (size_t)24 * N * sizeof(float) + 64;

    if (ws_size >= need) {
        float* st = (float*)d_ws;
        int* q0 = (int*)((char*)d_ws + (size_t)22 * N * sizeof(float));
        int* q1 = q0 + N;
        int* cnt = q1 + N;                       // 16 ints
        hipMemsetAsync(cnt, 0, 16 * sizeof(int), stream);

        hipLaunchKernelGGL(init_step1_kernel, dim3(nb), dim3(256), 0, stream,
                           xd, x_init, Jinv, tfs, W0, b0, W1, b1, W2, b2,
                           out, st, q0, &cnt[0], N);
        hipLaunchKernelGGL(step_kernel, dim3(nb), dim3(256), 0, stream,
                           xd, tfs, W0, b0, W1, b1, W2, b2, out, st,
                           q0, &cnt[0], q1, &cnt[1], N);
        hipLaunchKernelGGL(step_kernel, dim3(nb), dim3(256), 0, stream,
                           xd, tfs, W0, b0, W1, b1, W2, b2, out, st,
                           q1, &cnt[1], q0, &cnt[2], N);
        hipLaunchKernelGGL(tail_kernel, dim3(nb), dim3(256), 0, stream,
                           xd, tfs, W0, b0, W1, b1, W2, b2, out, st,
                           q0, &cnt[2], N);
    } else {
        hipLaunchKernelGGL(broyden_mono_kernel, dim3(nb), dim3(256), 0, stream,
                           xd, x_init, Jinv, tfs, W0, b0, W1, b1, W2, b2, out, N);
    }
}

// Round 14
// 311.091 us; speedup vs baseline: 1.3911x; 1.3911x over previous
//
#include <hip/hip_runtime.h>
#include <math.h>

#define NBLEND 24
#define HDIM 128
#define KQ 32                    // k-columns per wave (4-way split)
#define MAX_STEPS 10
#define CVG_T 1e-5f
#define DVG_T 1.0f
#define EPS_B 1e-6f

typedef float v2f __attribute__((ext_vector_type(2)));

#if __has_builtin(__builtin_elementwise_fma)
#define VFMA(a, b, c) __builtin_elementwise_fma((a), (b), (c))
#else
static __device__ __forceinline__ v2f VFMA(v2f a, v2f b, v2f c) {
    v2f r; r.x = fmaf(a.x, b.x, c.x); r.y = fmaf(a.y, b.y, c.y); return r;
}
#endif

__device__ __forceinline__ float softplus_f(float x) {
    // jax.nn.softplus: max(x,0) + log1p(exp(-|x|)), numerically stable
    float e = __expf(-fabsf(x));
    return fmaxf(x, 0.0f) + __logf(1.0f + e);
}

// One g(x) evaluation, 4-way k-split (R12 structure, 86% VALUBusy) PLUS
// h0 de-duplication through LDS: in R12 every wave recomputed all 128
// h0 softplus values (the 4x-duplicated ~1100 inst incl 256 quarter-rate
// transcendentals dominated issue). Now wave w computes only rows
// [w*32, w*32+32) -> LDS h[128][64] (lane-indexed, 2-way bank alias = free),
// and all waves read h back with conflict-free ds_read_b32. One producer,
// same ops, same order -> bit-identical g to R12 (which passed).
// The logit-exchange buffer aliases the h buffer (union, 32 KB), with
// barrier discipline. All four waves hold bit-identical results.
__device__ __forceinline__ void eval_g_quad(
    float* __restrict__ hbuf,     // 32 KB: h[128][64] / part[4][12][64] union
    int w, int lane,
    const float* __restrict__ W0, const float* __restrict__ b0,
    const float* __restrict__ W1, const float* __restrict__ b1,
    const float* __restrict__ W2, const float* __restrict__ b2,
    const float* __restrict__ tfs,
    float x0, float x1, float x2,
    float xd0, float xd1, float xd2,
    float& g0, float& g1, float& g2)
{
    v2f* part = (v2f*)hbuf;       // part[w][m2][lane] = part[(w*12+m2)*64+lane]
    v2f vx0 = {x0, x0}, vx1 = {x1, x1}, vx2 = {x2, x2};

    // ---- phase 1: own h0 slice -> LDS ----
    {
        const int jb = w * KQ;
        #pragma unroll 4
        for (int jj = 0; jj < KQ; jj += 2) {
            const int j = jb + jj;
            v2f z = *(const v2f*)(b0 + j);
            z = VFMA(vx0, *(const v2f*)(W0 + j), z);
            z = VFMA(vx1, *(const v2f*)(W0 + HDIM + j), z);
            z = VFMA(vx2, *(const v2f*)(W0 + 2 * HDIM + j), z);
            hbuf[j * 64 + lane]       = softplus_f(z.x);
            hbuf[(j + 1) * 64 + lane] = softplus_f(z.y);
        }
    }
    __syncthreads();   // h complete

    // ---- phase 2: rank-1 accumulate, h from LDS, W1 slice via s_load ----
    v2f acc[KQ / 2];
    {
        const v2f* __restrict__ b1v = (const v2f*)(b1 + w * KQ);
        #pragma unroll
        for (int kk = 0; kk < KQ / 2; ++kk) acc[kk] = b1v[kk];
    }
    const float* __restrict__ W1h = W1 + w * KQ;
    #pragma unroll 2
    for (int j = 0; j < HDIM; j += 2) {
        float ha = hbuf[j * 64 + lane];
        float hb = hbuf[(j + 1) * 64 + lane];
        const v2f* __restrict__ r0 = (const v2f*)(W1h + j * HDIM);
        const v2f* __restrict__ r1 = (const v2f*)(W1h + (j + 1) * HDIM);
        v2f hva = {ha, ha}, hvb = {hb, hb};
        #pragma unroll
        for (int kk = 0; kk < KQ / 2; ++kk) acc[kk] = VFMA(hva, r0[kk], acc[kk]);
        #pragma unroll
        for (int kk = 0; kk < KQ / 2; ++kk) acc[kk] = VFMA(hvb, r1[kk], acc[kk]);
    }
    #pragma unroll
    for (int kk = 0; kk < KQ / 2; ++kk) {
        acc[kk].x = softplus_f(acc[kk].x);
        acc[kk].y = softplus_f(acc[kk].y);
    }

    // raw partial logits over own k-slice (b2 added in fixed order below)
    v2f lgp[NBLEND / 2];
    #pragma unroll
    for (int m2 = 0; m2 < NBLEND / 2; ++m2) lgp[m2] = (v2f){0.f, 0.f};
    const float* __restrict__ W2h = W2 + w * KQ * NBLEND;
    #pragma unroll
    for (int kk = 0; kk < KQ; ++kk) {
        float h1 = (kk & 1) ? acc[kk >> 1].y : acc[kk >> 1].x;
        v2f hv = {h1, h1};
        const v2f* __restrict__ w2r = (const v2f*)(W2h + kk * NBLEND);
        #pragma unroll
        for (int m2 = 0; m2 < NBLEND / 2; ++m2) lgp[m2] = VFMA(hv, w2r[m2], lgp[m2]);
    }

    __syncthreads();   // all phase-2 h reads done; safe to overwrite via part
    #pragma unroll
    for (int m2 = 0; m2 < NBLEND / 2; ++m2) part[(w * 12 + m2) * 64 + lane] = lgp[m2];
    __syncthreads();
    v2f lg[NBLEND / 2];
    {
        const v2f* __restrict__ b2v = (const v2f*)b2;
        #pragma unroll
        for (int m2 = 0; m2 < NBLEND / 2; ++m2)
            lg[m2] = ((b2v[m2] + part[(0 * 12 + m2) * 64 + lane])
                      + part[(1 * 12 + m2) * 64 + lane])
                     + (part[(2 * 12 + m2) * 64 + lane]
                        + part[(3 * 12 + m2) * 64 + lane]);
    }
    __syncthreads();   // part reads done; next eval's phase-1 may overwrite

    // two-pass softmax over 24 logits (matches jax.nn.softmax)
    float M = -3.0e38f;
    #pragma unroll
    for (int m2 = 0; m2 < NBLEND / 2; ++m2)
        M = fmaxf(M, fmaxf(lg[m2].x, lg[m2].y));

    float S = 0.f;
    v2f T[6];
    #pragma unroll
    for (int t = 0; t < 6; ++t) T[t] = (v2f){0.f, 0.f};
    #pragma unroll
    for (int m = 0; m < NBLEND; ++m) {
        float lgm = (m & 1) ? lg[m >> 1].y : lg[m >> 1].x;
        float e = __expf(lgm - M);
        S += e;
        const v2f* __restrict__ tf = (const v2f*)(tfs + m * 12);
        v2f ev = {e, e};
        #pragma unroll
        for (int t = 0; t < 6; ++t) T[t] = VFMA(ev, tf[t], T[t]);
    }
    float inv = 1.0f / S;
    g0 = inv * fmaf(T[0].x, x0, fmaf(T[0].y, x1, fmaf(T[1].x, x2, T[1].y))) - xd0;
    g1 = inv * fmaf(T[2].x, x0, fmaf(T[2].y, x1, fmaf(T[3].x, x2, T[3].y))) - xd1;
    g2 = inv * fmaf(T[4].x, x0, fmaf(T[4].y, x1, fmaf(T[5].x, x2, T[5].y))) - xd2;
}

// Monolithic Broyden solver: 1 block = 4 waves = 64 points (R12 structure —
// block-ballot early exit already captures ~all of the convergence win;
// R13 proved compaction is a wash). All four waves carry bit-identical
// state -> identical ballot -> uniform break, barriers aligned. Frozen
// lanes take dx=0: exact fixed point (dg=0 -> a=0 -> iu=0; NaN via selects).
__global__ void __launch_bounds__(256)
broyden_quad_kernel(const float* __restrict__ xd_p,
                    const float* __restrict__ x_init,
                    const float* __restrict__ Jinv_init,
                    const float* __restrict__ tfs,
                    const float* __restrict__ W0, const float* __restrict__ b0,
                    const float* __restrict__ W1, const float* __restrict__ b1,
                    const float* __restrict__ W2, const float* __restrict__ b2,
                    float* __restrict__ out, int N)
{
    __shared__ __align__(16) float hbuf[HDIM * 64];   // 32 KB (h / part union)
    const int tid = threadIdx.x;
    const int lane = tid & 63;
    const int w = __builtin_amdgcn_readfirstlane(tid >> 6);   // 0..3
    const int n = blockIdx.x * 64 + lane;    // N = 131072 = 2048*64 exact

    float xd0 = xd_p[n * 3 + 0], xd1 = xd_p[n * 3 + 1], xd2 = xd_p[n * 3 + 2];
    float x0 = x_init[n * 3 + 0], x1 = x_init[n * 3 + 1], x2 = x_init[n * 3 + 2];
    float J0 = Jinv_init[n * 9 + 0], J1 = Jinv_init[n * 9 + 1], J2 = Jinv_init[n * 9 + 2];
    float J3 = Jinv_init[n * 9 + 3], J4 = Jinv_init[n * 9 + 4], J5 = Jinv_init[n * 9 + 5];
    float J6 = Jinv_init[n * 9 + 6], J7 = Jinv_init[n * 9 + 7], J8 = Jinv_init[n * 9 + 8];

    float g0, g1, g2;
    eval_g_quad(hbuf, w, lane, W0, b0, W1, b1, W2, b2, tfs,
                x0, x1, x2, xd0, xd1, xd2, g0, g1, g2);

    float u0 = -(fmaf(J0, g0, fmaf(J1, g1, J2 * g2)));
    float u1 = -(fmaf(J3, g0, fmaf(J4, g1, J5 * g2)));
    float u2 = -(fmaf(J6, g0, fmaf(J7, g1, J8 * g2)));

    float gn_opt = sqrtf(g0 * g0 + g1 * g1 + g2 * g2);
    float xo0 = x0, xo1 = x1, xo2 = x2;
    bool ids = true;   // reference initializes ids = ones(bool)

    for (int step = 0; step < MAX_STEPS; ++step) {
        // identical ids in all 4 waves -> identical ballot -> uniform break
        if (__ballot(ids) == 0ull) break;

        float dx0 = ids ? u0 : 0.f, dx1 = ids ? u1 : 0.f, dx2 = ids ? u2 : 0.f;
        x0 += dx0; x1 += dx1; x2 += dx2;

        float ng0, ng1, ng2;
        eval_g_quad(hbuf, w, lane, W0, b0, W1, b1, W2, b2, tfs,
                    x0, x1, x2, xd0, xd1, xd2, ng0, ng1, ng2);
        float dg0 = ng0 - g0, dg1 = ng1 - g1, dg2 = ng2 - g2;
        g0 = ng0; g1 = ng1; g2 = ng2;

        float gn = sqrtf(g0 * g0 + g1 * g1 + g2 * g2);
        bool better = gn < gn_opt;              // false for NaN (matches jnp.where)
        if (better) { gn_opt = gn; xo0 = x0; xo1 = x1; xo2 = x2; }
        bool ids_new = (gn_opt > CVG_T) && (gn < DVG_T);

        float vT0 = fmaf(dx0, J0, fmaf(dx1, J3, dx2 * J6));
        float vT1 = fmaf(dx0, J1, fmaf(dx1, J4, dx2 * J7));
        float vT2 = fmaf(dx0, J2, fmaf(dx1, J5, dx2 * J8));
        float a0 = dx0 - fmaf(J0, dg0, fmaf(J1, dg1, J2 * dg2));
        float a1 = dx1 - fmaf(J3, dg0, fmaf(J4, dg1, J5 * dg2));
        float a2 = dx2 - fmaf(J6, dg0, fmaf(J7, dg1, J8 * dg2));
        float bb = fmaf(vT0, dg0, fmaf(vT1, dg1, vT2 * dg2));
        bb += (bb >= 0.f) ? EPS_B : -EPS_B;
        // select (NOT multiply) so NaN can't leak into J when masked off
        float iu0 = ids_new ? (a0 / bb) : 0.f;
        float iu1 = ids_new ? (a1 / bb) : 0.f;
        float iu2 = ids_new ? (a2 / bb) : 0.f;
        J0 = fmaf(iu0, vT0, J0); J1 = fmaf(iu0, vT1, J1); J2 = fmaf(iu0, vT2, J2);
        J3 = fmaf(iu1, vT0, J3); J4 = fmaf(iu1, vT1, J4); J5 = fmaf(iu1, vT2, J5);
        J6 = fmaf(iu2, vT0, J6); J7 = fmaf(iu2, vT1, J7); J8 = fmaf(iu2, vT2, J8);

        u0 = -(fmaf(J0, g0, fmaf(J1, g1, J2 * g2)));
        u1 = -(fmaf(J3, g0, fmaf(J4, g1, J5 * g2)));
        u2 = -(fmaf(J6, g0, fmaf(J7, g1, J8 * g2)));
        ids = ids_new;
    }

    // outputs: x_opt (N,3,1) | gn_opt (N) | valid (N) as 0.0/1.0
    if (w == 0) {
        out[n * 3 + 0] = xo0;
        out[n * 3 + 1] = xo1;
        out[n * 3 + 2] = xo2;
        out[3 * N + n] = gn_opt;
        out[4 * N + n] = (gn_opt < CVG_T) ? 1.0f : 0.0f;
    }
}

extern "C" void kernel_launch(void* const* d_in, const int* in_sizes, int n_in,
                              void* d_out, int out_size, void* d_ws, size_t ws_size,
                              hipStream_t stream) {
    const float* xd     = (const float*)d_in[0];
    const float* x_init = (const float*)d_in[1];
    const float* Jinv   = (const float*)d_in[2];
    const float* tfs    = (const float*)d_in[3];
    const float* W0     = (const float*)d_in[4];
    const float* b0     = (const float*)d_in[5];
    const float* W1     = (const float*)d_in[6];
    const float* b1     = (const float*)d_in[7];
    const float* W2     = (const float*)d_in[8];
    const float* b2     = (const float*)d_in[9];
    float* out = (float*)d_out;

    const int N = in_sizes[0] / 3;
    dim3 block(256);                 // 4 waves, 64 points per block
    dim3 grid((N + 63) / 64);

    hipLaunchKernelGGL(broyden_quad_kernel, grid, block, 0, stream,
                       xd, x_init, Jinv, tfs, W0, b0, W1, b1, W2, b2, out, N);
}